// Round 9
// baseline (262.780 us; speedup 1.0000x reference)
//
#include <hip/hip_runtime.h>

// Problem constants (setup_inputs fixed: N=4, Lq=6400, C=256, H=W=80)
#define NB    4
#define LQ    6400
#define CC    256
#define HH    80
#define WW    80
#define HWSZ  (HH*WW)
#define RTOT  (NB*LQ)        // 25600 rows
#define HID   1024

typedef __attribute__((ext_vector_type(8))) short bf16x8;   // 8 bf16 = 4 VGPRs
typedef __attribute__((ext_vector_type(4))) float f32x4;

__device__ __forceinline__ float bf2f(unsigned short u) {
    unsigned int i = ((unsigned int)u) << 16;
    float f; __builtin_memcpy(&f, &i, 4); return f;
}
__device__ __forceinline__ unsigned short f2bf(float f) {
    unsigned int i; __builtin_memcpy(&i, &f, 4);
    unsigned int r = i + 0x7fffu + ((i >> 16) & 1u);   // RNE
    return (unsigned short)(r >> 16);
}

// ---------------- fused prep: value cvt + all weight swizzles + bias cat ----------------
// swizzle layout: group g -> n = g%N, kq = g/N, kbase = (kq>>2)*32 + (kq&3)*8;
// dst[g*8+j] = bf16(src[(kbase+j)*N + n])  — the exact VGPR image an A-fragment wants.
__global__ void prepcvt_k(const float* __restrict__ value, unsigned short* __restrict__ val_b,
                          const float* __restrict__ Wv,   const float* __restrict__ Wout,
                          const float* __restrict__ W1,   const float* __restrict__ W2,
                          const float* __restrict__ Woff, const float* __restrict__ Wa,
                          const float* __restrict__ boff, const float* __restrict__ ba,
                          unsigned short* __restrict__ wvS,  unsigned short* __restrict__ woutS,
                          unsigned short* __restrict__ w1s,  unsigned short* __restrict__ w2s,
                          unsigned short* __restrict__ woas, float* __restrict__ b_oa) {
    int b = blockIdx.x;
    if (b < 6400) {                              // value fp32 -> bf16 (1,638,400 x4 elems)
        int i = b * 256 + threadIdx.x;
        float4 u = ((const float4*)value)[i];
        ushort4 o;
        o.x = f2bf(u.x); o.y = f2bf(u.y); o.z = f2bf(u.z); o.w = f2bf(u.w);
        ((ushort4*)val_b)[i] = o;
        return;
    }
    int idx = (b - 6400) * 256 + threadIdx.x;
    if (idx < 8192) {                            // wvS swizzle (K=256, N=256)
        int n = idx & 255, kq = idx >> 8;
        int kb = (kq >> 2) * 32 + (kq & 3) * 8;
        unsigned short* d = wvS + (size_t)idx * 8;
        #pragma unroll
        for (int j = 0; j < 8; ++j) d[j] = f2bf(Wv[(size_t)(kb + j) * 256 + n]);
        return;
    }
    idx -= 8192;
    if (idx < 32768) {                           // w1s swizzle (K=256, N=1024)
        int n = idx & 1023, kq = idx >> 10;
        int kb = (kq >> 2) * 32 + (kq & 3) * 8;
        unsigned short* d = w1s + (size_t)idx * 8;
        #pragma unroll
        for (int j = 0; j < 8; ++j) d[j] = f2bf(W1[(size_t)(kb + j) * 1024 + n]);
        return;
    }
    idx -= 32768;
    if (idx < 32768) {                           // w2s swizzle (K=1024, N=256)
        int n = idx & 255, kq = idx >> 8;
        int kb = (kq >> 2) * 32 + (kq & 3) * 8;
        unsigned short* d = w2s + (size_t)idx * 8;
        #pragma unroll
        for (int j = 0; j < 8; ++j) d[j] = f2bf(W2[(size_t)(kb + j) * 256 + n]);
        return;
    }
    idx -= 32768;
    if (idx < 8192) {                            // woutS swizzle (K=256, N=256)
        int n = idx & 255, kq = idx >> 8;
        int kb = (kq >> 2) * 32 + (kq & 3) * 8;
        unsigned short* d = woutS + (size_t)idx * 8;
        #pragma unroll
        for (int j = 0; j < 8; ++j) d[j] = f2bf(Wout[(size_t)(kb + j) * 256 + n]);
        return;
    }
    idx -= 8192;
    if (idx < 4096) {                            // woas swizzle (K=256, Npad=128: Woff|Wa|0)
        int n = idx & 127, kq = idx >> 7;
        int kb = (kq >> 2) * 32 + (kq & 3) * 8;
        unsigned short* d = woas + (size_t)idx * 8;
        #pragma unroll
        for (int j = 0; j < 8; ++j) {
            float v = 0.f;
            if (n < 64)      v = Woff[(size_t)(kb + j) * 64 + n];
            else if (n < 96) v = Wa[(size_t)(kb + j) * 32 + (n - 64)];
            d[j] = f2bf(v);
        }
        return;
    }
    idx -= 4096;
    if (idx < 96) b_oa[idx] = idx < 64 ? boff[idx] : ba[idx - 64];
}

// ---------------- shared LN stage: 64 rows fp32 -> fragment-major bf16 hblob ----------
// 512 threads: 8 threads/row; hblob 32 kq x 1040 B stride (odd 16B-granule -> bank-clean).
__device__ __forceinline__ void ln_stage(const float* __restrict__ xbase,  // + row0*CC
                                         const float* __restrict__ lw,
                                         const float* __restrict__ lb,
                                         unsigned short* hblob, int t) {
    int r = t >> 3, sub = t & 7;
    const float* xr = xbase + (size_t)r * CC;
    float4 xv[4][2];
    float s = 0.f, s2 = 0.f;
    #pragma unroll
    for (int jj = 0; jj < 4; ++jj) {
        #pragma unroll
        for (int u = 0; u < 2; ++u) {
            float4 v = *(const float4*)(xr + sub * 8 + jj * 64 + u * 4);
            xv[jj][u] = v;
            s  += v.x + v.y + v.z + v.w;
            s2 += v.x*v.x + v.y*v.y + v.z*v.z + v.w*v.w;
        }
    }
    #pragma unroll
    for (int m = 1; m < 8; m <<= 1) {
        s  += __shfl_xor(s,  m);
        s2 += __shfl_xor(s2, m);
    }
    float mean = s * (1.0f / CC);
    float var  = s2 * (1.0f / CC) - mean * mean;
    float rstd = rsqrtf(fmaxf(var, 0.0f) + 1e-5f);
    #pragma unroll
    for (int jj = 0; jj < 4; ++jj) {
        int c0 = sub * 8 + jj * 64;
        float4 w0 = *(const float4*)(lw + c0);
        float4 w1 = *(const float4*)(lw + c0 + 4);
        float4 bb0 = *(const float4*)(lb + c0);
        float4 bb1 = *(const float4*)(lb + c0 + 4);
        bf16x8 o;
        o[0] = (short)f2bf((xv[jj][0].x - mean) * rstd * w0.x + bb0.x);
        o[1] = (short)f2bf((xv[jj][0].y - mean) * rstd * w0.y + bb0.y);
        o[2] = (short)f2bf((xv[jj][0].z - mean) * rstd * w0.z + bb0.z);
        o[3] = (short)f2bf((xv[jj][0].w - mean) * rstd * w0.w + bb0.w);
        o[4] = (short)f2bf((xv[jj][1].x - mean) * rstd * w1.x + bb1.x);
        o[5] = (short)f2bf((xv[jj][1].y - mean) * rstd * w1.y + bb1.y);
        o[6] = (short)f2bf((xv[jj][1].z - mean) * rstd * w1.z + bb1.z);
        o[7] = (short)f2bf((xv[jj][1].w - mean) * rstd * w1.w + bb1.w);
        int kq = sub + jj * 8;
        *(bf16x8*)((char*)hblob + kq * 1040 + r * 16) = o;
    }
}

// ---------------- fused value-projection + LN1/offsets dispatch ----------------
// blocks [0,400): v = val @ Wv + bv (stage rows -> hblob, MFMA with wvS, bf16 out)
// blocks [400,800): oa = LN1(x) @ [Woff|Wa] + b_oa
__global__ __launch_bounds__(512) void pl_k(
        const unsigned short* __restrict__ val_b, const unsigned short* __restrict__ wvS,
        const float* __restrict__ bv,
        const float* __restrict__ x, const float* __restrict__ lw, const float* __restrict__ lb,
        const unsigned short* __restrict__ woas, const float* __restrict__ b_oa,
        unsigned short* __restrict__ v_b, unsigned short* __restrict__ oa) {
    __shared__ char lds_raw[66560];
    unsigned short* hblob = (unsigned short*)lds_raw;            // 32 kq x 1040 B
    float* trans = (float*)lds_raw;                              // alias (epilogue)

    int b = blockIdx.x;
    int t = threadIdx.x;
    int lane = t & 63, wave = t >> 6;
    int quad = lane >> 4, l16 = lane & 15;

    if (b < 400) {
        int row0 = b * 64;
        // stage 64x256 bf16 rows into fragment-major hblob
        {
            int kq = t & 31, rb = t >> 5;        // rb 0..15
            #pragma unroll
            for (int i = 0; i < 4; ++i) {
                int r = i * 16 + rb;
                bf16x8 u = *(const bf16x8*)(val_b + (size_t)(row0 + r) * CC + kq * 8);
                *(bf16x8*)((char*)hblob + kq * 1040 + r * 16) = u;
            }
        }
        __syncthreads();
        // K=256 MFMA: 8 waves x 32 cols
        f32x4 acc[2][4];
        #pragma unroll
        for (int a = 0; a < 2; ++a)
            #pragma unroll
            for (int q = 0; q < 4; ++q)
                acc[a][q] = (f32x4){0.f, 0.f, 0.f, 0.f};
        #pragma unroll
        for (int kb = 0; kb < 8; ++kb) {
            bf16x8 a2[2], bf[4];
            #pragma unroll
            for (int ct = 0; ct < 2; ++ct)
                a2[ct] = *(const bf16x8*)(wvS + ((size_t)(kb * 4 + quad) * 256 + wave * 32 + ct * 16 + l16) * 8);
            #pragma unroll
            for (int qt = 0; qt < 4; ++qt)
                bf[qt] = *(const bf16x8*)((char*)hblob + (kb * 4 + quad) * 1040 + (qt * 16 + l16) * 16);
            #pragma unroll
            for (int ct = 0; ct < 2; ++ct)
                #pragma unroll
                for (int qt = 0; qt < 4; ++qt)
                    acc[ct][qt] = __builtin_amdgcn_mfma_f32_16x16x32_bf16(a2[ct], bf[qt], acc[ct][qt], 0, 0, 0);
        }
        __syncthreads();                         // all MFMA reads of hblob done before alias
        #pragma unroll
        for (int qt = 0; qt < 4; ++qt) {
            int qrow = qt * 16 + l16;
            #pragma unroll
            for (int ct = 0; ct < 2; ++ct) {
                int c4 = wave * 8 + ct * 4 + quad;
                *(f32x4*)(trans + qrow * 260 + c4 * 4) = acc[ct][qt];
            }
        }
        __syncthreads();
        {
            int rr = t >> 3, c4b = t & 7;
            #pragma unroll
            for (int i = 0; i < 8; ++i) {
                int c4 = i * 8 + c4b;
                f32x4 vv = *(const f32x4*)(trans + rr * 260 + c4 * 4);
                float4 bb = *(const float4*)(bv + c4 * 4);
                ushort4 o;
                o.x = f2bf(vv[0] + bb.x);
                o.y = f2bf(vv[1] + bb.y);
                o.z = f2bf(vv[2] + bb.z);
                o.w = f2bf(vv[3] + bb.w);
                *(ushort4*)(v_b + (size_t)(row0 + rr) * CC + c4 * 4) = o;
            }
        }
    } else {
        int row0 = (b - 400) * 64;
        ln_stage(x + (size_t)row0 * CC, lw, lb, hblob, t);
        __syncthreads();
        if (wave < 6) {
            f32x4 acc[4];
            #pragma unroll
            for (int qt = 0; qt < 4; ++qt) acc[qt] = (f32x4){0.f, 0.f, 0.f, 0.f};
            #pragma unroll
            for (int kb = 0; kb < 8; ++kb) {
                bf16x8 a1 = *(const bf16x8*)(woas + ((size_t)(kb * 4 + quad) * 128 + wave * 16 + l16) * 8);
                #pragma unroll
                for (int qt = 0; qt < 4; ++qt) {
                    bf16x8 bf = *(const bf16x8*)((char*)hblob + (kb * 4 + quad) * 1040 + (qt * 16 + l16) * 16);
                    acc[qt] = __builtin_amdgcn_mfma_f32_16x16x32_bf16(a1, bf, acc[qt], 0, 0, 0);
                }
            }
            int n0 = wave * 16 + quad * 4;
            float4 bb = *(const float4*)(b_oa + n0);
            const float* bp = (const float*)&bb;
            #pragma unroll
            for (int qt = 0; qt < 4; ++qt) {
                unsigned long long pk = 0;
                #pragma unroll
                for (int r = 0; r < 4; ++r)
                    pk |= ((unsigned long long)f2bf(acc[qt][r] + bp[r])) << (16 * r);
                *(unsigned long long*)(oa + (size_t)(row0 + qt * 16 + l16) * 96 + n0) = pk;
            }
        }
    }
}

// ---------------- fused sampling + Wout GEMM + residual: x2 = x + samp@Wout + bout -----
__global__ __launch_bounds__(512) void samwout_k(
        const unsigned short* __restrict__ v,    // (NB, HW, C) bf16
        const float* __restrict__ ref,           // (R, 2) fp32
        const unsigned short* __restrict__ oa,   // (R, 96) bf16
        const unsigned short* __restrict__ woutS,
        const float* __restrict__ bout,
        const float* __restrict__ x,             // residual fp32
        float* __restrict__ x2) {
    __shared__ char lds_raw[57856];
    unsigned short* hblob = (unsigned short*)lds_raw;            // 32 kq x 1040 B
    short4* sidx = (short4*)(lds_raw + 33280);                   // 1024 x 8 B
    float4* sw   = (float4*)(lds_raw + 41472);                   // 1024 x 16 B
    float* trans = (float*)lds_raw;                              // alias (epilogue, 32x260)

    int t = threadIdx.x;
    int lane = t & 63, wave = t >> 6;
    int quad = lane >> 4, l16 = lane & 15;
    int row0 = blockIdx.x * 64;
    int nb = blockIdx.x / (LQ / 64);             // batch, block-uniform

    for (int half = 0; half < 2; ++half) {
        int rbase = half * 32;
        #pragma unroll
        for (int s = 0; s < 2; ++s) {
            int e = t + s * 512;
            int q = e >> 5, sub = e & 31, h = sub >> 2, p = sub & 3;
            int row = row0 + rbase + q;
            float refx = ref[row * 2 + 0];
            float refy = ref[row * 2 + 1];
            const unsigned short* oar = oa + (size_t)row * 96;
            float ox = bf2f(oar[(h * 4 + p) * 2 + 0]);
            float oy = bf2f(oar[(h * 4 + p) * 2 + 1]);
            float l  = bf2f(oar[64 + h * 4 + p]);
            float m = fmaxf(l, __shfl_xor(l, 1));
            m = fmaxf(m, __shfl_xor(m, 2));
            float ee = __expf(l - m);
            float ss = ee + __shfl_xor(ee, 1);
            ss = ss + __shfl_xor(ss, 2);
            float wp = ee / ss;

            float gx = (refx + ox * (1.0f / WW)) * WW - 0.5f;
            float gy = (refy + oy * (1.0f / HH)) * HH - 0.5f;
            float fx = floorf(gx), fy = floorf(gy);
            float wx = gx - fx, wy = gy - fy;
            int x0 = (int)fx, y0 = (int)fy;
            int x1 = x0 + 1, y1 = y0 + 1;
            bool vx0 = (unsigned)x0 < WW, vx1 = (unsigned)x1 < WW;
            bool vy0 = (unsigned)y0 < HH, vy1 = (unsigned)y1 < HH;
            float w00 = (vx0 && vy0) ? wp * (1.f - wx) * (1.f - wy) : 0.f;
            float w10 = (vx1 && vy0) ? wp * wx * (1.f - wy)         : 0.f;
            float w01 = (vx0 && vy1) ? wp * (1.f - wx) * wy         : 0.f;
            float w11 = (vx1 && vy1) ? wp * wx * wy                 : 0.f;
            int cx0 = min(max(x0, 0), WW - 1), cx1 = min(max(x1, 0), WW - 1);
            int cy0 = min(max(y0, 0), HH - 1), cy1 = min(max(y1, 0), HH - 1);
            sidx[e] = (short4){(short)(cy0 * WW + cx0), (short)(cy0 * WW + cx1),
                               (short)(cy1 * WW + cx0), (short)(cy1 * WW + cx1)};
            sw[e]   = (float4){w00, w10, w01, w11};
        }
        __syncthreads();
        #pragma unroll
        for (int s = 0; s < 2; ++s) {
            int c = t + s * 512;
            int q = c >> 5, sub = c & 31, h = sub >> 2, cg = sub & 3;
            const unsigned short* base = v + (size_t)nb * HWSZ * CC + h * 32 + cg * 8;
            float acc[8];
            #pragma unroll
            for (int j = 0; j < 8; ++j) acc[j] = 0.f;
            #pragma unroll
            for (int p = 0; p < 4; ++p) {
                int e = q * 32 + h * 4 + p;
                short4 I = sidx[e];
                float4 Wt = sw[e];
                const short* Ip = (const short*)&I;
                const float* Wp = (const float*)&Wt;
                #pragma unroll
                for (int cn = 0; cn < 4; ++cn) {
                    bf16x8 u = *(const bf16x8*)(base + (size_t)(unsigned short)Ip[cn] * CC);
                    float wgt = Wp[cn];
                    #pragma unroll
                    for (int j = 0; j < 8; ++j)
                        acc[j] += wgt * bf2f((unsigned short)u[j]);
                }
            }
            bf16x8 o;
            #pragma unroll
            for (int j = 0; j < 8; ++j) o[j] = (short)f2bf(acc[j]);
            *(bf16x8*)((char*)hblob + sub * 1040 + (rbase + q) * 16) = o;
        }
        __syncthreads();
    }

    // ---- Wout MFMA: K=256, 8 waves x 32 cols ----
    f32x4 acc2[2][4];
    #pragma unroll
    for (int a = 0; a < 2; ++a)
        #pragma unroll
        for (int b = 0; b < 4; ++b)
            acc2[a][b] = (f32x4){0.f, 0.f, 0.f, 0.f};
    #pragma unroll
    for (int kb = 0; kb < 8; ++kb) {
        bf16x8 a2[2], bf[4];
        #pragma unroll
        for (int ct = 0; ct < 2; ++ct)
            a2[ct] = *(const bf16x8*)(woutS + ((size_t)(kb * 4 + quad) * 256 + wave * 32 + ct * 16 + l16) * 8);
        #pragma unroll
        for (int qt = 0; qt < 4; ++qt)
            bf[qt] = *(const bf16x8*)((char*)hblob + (kb * 4 + quad) * 1040 + (qt * 16 + l16) * 16);
        #pragma unroll
        for (int ct = 0; ct < 2; ++ct)
            #pragma unroll
            for (int qt = 0; qt < 4; ++qt)
                acc2[ct][qt] = __builtin_amdgcn_mfma_f32_16x16x32_bf16(a2[ct], bf[qt], acc2[ct][qt], 0, 0, 0);
    }

    for (int p = 0; p < 2; ++p) {
        __syncthreads();
        #pragma unroll
        for (int qi = 0; qi < 2; ++qi) {
            int qt = p * 2 + qi;
            int qlocal = qt * 16 + l16 - p * 32;
            #pragma unroll
            for (int ct = 0; ct < 2; ++ct) {
                int c4 = wave * 8 + ct * 4 + quad;
                *(f32x4*)(trans + qlocal * 260 + c4 * 4) = acc2[ct][qt];
            }
        }
        __syncthreads();
        int rr = t >> 4;
        int c4b = t & 15;
        int row = row0 + p * 32 + rr;
        #pragma unroll
        for (int i = 0; i < 4; ++i) {
            int c4 = i * 16 + c4b;
            f32x4 vv = *(const f32x4*)(trans + rr * 260 + c4 * 4);
            int c = c4 * 4;
            float4 xv = *(const float4*)(x + (size_t)row * CC + c);
            float4 bb = *(const float4*)(bout + c);
            float4 o;
            o.x = vv[0] + xv.x + bb.x;
            o.y = vv[1] + xv.y + bb.y;
            o.z = vv[2] + xv.z + bb.z;
            o.w = vv[3] + xv.w + bb.w;
            *(float4*)(x2 + (size_t)row * CC + c) = o;
        }
    }
}

// ---------------- fused LN2 + MLP, producer/consumer waves ----------------
// Block = 64 rows, 512 thr. Waves 0-3 PRODUCE gelu(h1) chunks (32 hidden each,
// 0.5 LDS-read/MFMA); waves 4-7 CONSUME (64 cols each, 0.25 LDS-read/MFMA).
// s1(hc+1) and s2(hc) overlap between single barriers on disjoint dbuf halves.
__global__ __launch_bounds__(512) void mlp_k(
        const float* __restrict__ x2,
        const float* __restrict__ lw,
        const float* __restrict__ lb,
        const unsigned short* __restrict__ w1s,  // swizzled (256x1024)
        const float* __restrict__ b1,
        const unsigned short* __restrict__ w2s,  // swizzled (1024x256)
        const float* __restrict__ b2,
        float* __restrict__ out) {
    __shared__ char lds_raw[66560];
    unsigned short* hblob = (unsigned short*)lds_raw;            // 32 kq x 1040 B
    unsigned short* h1b0  = (unsigned short*)(lds_raw + 33280);  // 16 kq x 1040 B
    unsigned short* h1b1  = (unsigned short*)(lds_raw + 49920);  // 16 kq x 1040 B
    float* trans = (float*)lds_raw;                              // epilogue alias

    int t = threadIdx.x;
    int lane = t & 63, wave = t >> 6;
    int quad = lane >> 4, l16 = lane & 15;
    int row0 = blockIdx.x * 64;
    bool producer = wave < 4;
    int pw = wave & 3;                           // role-local wave index

    ln_stage(x2 + (size_t)row0 * CC, lw, lb, hblob, t);

    f32x4 acc2[4][4];                            // consumers: [ct][qt]
    #pragma unroll
    for (int a = 0; a < 4; ++a)
        #pragma unroll
        for (int b = 0; b < 4; ++b)
            acc2[a][b] = (f32x4){0.f, 0.f, 0.f, 0.f};

    auto s1 = [&](int hc, unsigned short* dst) {
        f32x4 a[2][4];
        #pragma unroll
        for (int ht = 0; ht < 2; ++ht)
            #pragma unroll
            for (int qt = 0; qt < 4; ++qt) a[ht][qt] = (f32x4){0.f, 0.f, 0.f, 0.f};
        #pragma unroll
        for (int kb = 0; kb < 8; ++kb) {
            bf16x8 a1[2], bf[4];
            #pragma unroll
            for (int ht = 0; ht < 2; ++ht)
                a1[ht] = *(const bf16x8*)(w1s + ((size_t)(kb * 4 + quad) * 1024 + hc * 128 + pw * 32 + ht * 16 + l16) * 8);
            #pragma unroll
            for (int qt = 0; qt < 4; ++qt)
                bf[qt] = *(const bf16x8*)((char*)hblob + (kb * 4 + quad) * 1040 + (qt * 16 + l16) * 16);
            #pragma unroll
            for (int ht = 0; ht < 2; ++ht)
                #pragma unroll
                for (int qt = 0; qt < 4; ++qt)
                    a[ht][qt] = __builtin_amdgcn_mfma_f32_16x16x32_bf16(a1[ht], bf[qt], a[ht][qt], 0, 0, 0);
        }
        #pragma unroll
        for (int ht = 0; ht < 2; ++ht) {
            int hl = pw * 32 + ht * 16 + quad * 4;     // hidden local in chunk, 0..127
            float4 bb = *(const float4*)(b1 + hc * 128 + hl);
            const float* bp = (const float*)&bb;
            #pragma unroll
            for (int qt = 0; qt < 4; ++qt) {
                unsigned long long pk = 0;
                #pragma unroll
                for (int r = 0; r < 4; ++r) {
                    float val = a[ht][qt][r] + bp[r];
                    val = 0.5f * val * (1.0f + erff(val * 0.70710678118654752f));
                    pk |= ((unsigned long long)f2bf(val)) << (16 * r);
                }
                *(unsigned long long*)((char*)dst + (hl >> 3) * 1040 + (qt * 16 + l16) * 16 + (hl & 7) * 2) = pk;
            }
        }
    };

    auto s2 = [&](int hc, const unsigned short* src) {
        #pragma unroll
        for (int k2 = 0; k2 < 4; ++k2) {
            bf16x8 a2[4], bf[4];
            #pragma unroll
            for (int ct = 0; ct < 4; ++ct)
                a2[ct] = *(const bf16x8*)(w2s + ((size_t)((hc * 4 + k2) * 4 + quad) * 256 + pw * 64 + ct * 16 + l16) * 8);
            #pragma unroll
            for (int qt = 0; qt < 4; ++qt)
                bf[qt] = *(const bf16x8*)((const char*)src + (k2 * 4 + quad) * 1040 + (qt * 16 + l16) * 16);
            #pragma unroll
            for (int ct = 0; ct < 4; ++ct)
                #pragma unroll
                for (int qt = 0; qt < 4; ++qt)
                    acc2[ct][qt] = __builtin_amdgcn_mfma_f32_16x16x32_bf16(a2[ct], bf[qt], acc2[ct][qt], 0, 0, 0);
        }
    };

    __syncthreads();                             // hblob ready
    if (producer) s1(0, h1b0);
    __syncthreads();
    for (int hc = 0; hc < 8; ++hc) {
        const unsigned short* cur = (hc & 1) ? h1b1 : h1b0;
        unsigned short*       nxt = (hc & 1) ? h1b0 : h1b1;
        if (producer) { if (hc < 7) s1(hc + 1, nxt); }
        else          s2(hc, cur);
        __syncthreads();
    }

    // ---- epilogue: consumers -> trans, all threads store out = mlp + x2 + b2 ----
    if (!producer) {
        #pragma unroll
        for (int qt = 0; qt < 4; ++qt) {
            int qrow = qt * 16 + l16;
            #pragma unroll
            for (int ct = 0; ct < 4; ++ct) {
                int c4 = pw * 16 + ct * 4 + quad;
                *(f32x4*)(trans + qrow * 260 + c4 * 4) = acc2[ct][qt];
            }
        }
    }
    __syncthreads();
    {
        int rr = t >> 3, c4b = t & 7;
        int row = row0 + rr;
        #pragma unroll
        for (int i = 0; i < 8; ++i) {
            int c4 = i * 8 + c4b;
            f32x4 v = *(const f32x4*)(trans + rr * 260 + c4 * 4);
            int c = c4 * 4;
            float4 xv = *(const float4*)(x2 + (size_t)row * CC + c);
            float4 bb = *(const float4*)(b2 + c);
            float4 o;
            o.x = v[0] + xv.x + bb.x;
            o.y = v[1] + xv.y + bb.y;
            o.z = v[2] + xv.z + bb.z;
            o.w = v[3] + xv.w + bb.w;
            *(float4*)(out + (size_t)row * CC + c) = o;
        }
    }
}

extern "C" void kernel_launch(void* const* d_in, const int* in_sizes, int n_in,
                              void* d_out, int out_size, void* d_ws, size_t ws_size,
                              hipStream_t stream) {
    const float* x     = (const float*)d_in[0];
    const float* ref   = (const float*)d_in[1];
    const float* value = (const float*)d_in[2];
    const float* ln1w  = (const float*)d_in[5];
    const float* ln1b  = (const float*)d_in[6];
    const float* ln2w  = (const float*)d_in[7];
    const float* ln2b  = (const float*)d_in[8];
    const float* Wv    = (const float*)d_in[9];
    const float* bv    = (const float*)d_in[10];
    const float* Woff  = (const float*)d_in[11];
    const float* boff  = (const float*)d_in[12];
    const float* Wa    = (const float*)d_in[13];
    const float* ba    = (const float*)d_in[14];
    const float* Wout  = (const float*)d_in[15];
    const float* bout  = (const float*)d_in[16];
    const float* W1    = (const float*)d_in[17];
    const float* b1    = (const float*)d_in[18];
    const float* W2    = (const float*)d_in[19];
    const float* b2    = (const float*)d_in[20];

    // ---- workspace layout (bytes), peak ~58.7 MB ----
    char* ws = (char*)d_ws;
    unsigned short* wvs_b  = (unsigned short*)(ws + 0);          // 131072
    unsigned short* wouts_b= (unsigned short*)(ws + 131072);     // 131072
    unsigned short* w1s_b  = (unsigned short*)(ws + 262144);     // 524288
    unsigned short* w2s_b  = (unsigned short*)(ws + 786432);     // 524288
    unsigned short* woas_b = (unsigned short*)(ws + 1310720);    // 65536
    float*          b_oa   = (float*)         (ws + 1376256);    // 512
    float*          x2_f   = (float*)         (ws + 1376768);    // 26,214,400
    unsigned short* val_b  = (unsigned short*)(ws + 27591168);   // 13,107,200
    unsigned short* v_b    = (unsigned short*)(ws + 40698368);   // 13,107,200
    unsigned short* oa_b   = (unsigned short*)(ws + 53805568);   // 4,915,200 -> 58,720,768

    // 1) value cvt + weight prep (single dispatch; 6400 cvt blocks + 337 prep blocks)
    prepcvt_k<<<6737, 256, 0, stream>>>(value, val_b, Wv, Wout, W1, W2, Woff, Wa, boff, ba,
                                        wvs_b, wouts_b, w1s_b, w2s_b, woas_b, b_oa);
    // 2) value projection (blocks 0-399) + LN1/offsets/logits (blocks 400-799)
    pl_k<<<800, 512, 0, stream>>>(val_b, wvs_b, bv, x, ln1w, ln1b, woas_b, b_oa, v_b, oa_b);
    // 3) sampling + Wout + residual(x) -> x2
    samwout_k<<<RTOT/64, 512, 0, stream>>>(v_b, ref, oa_b, wouts_b, bout, x, x2_f);
    // 4) LN2 + MLP (producer/consumer waves) -> out
    mlp_k<<<RTOT/64, 512, 0, stream>>>(x2_f, ln2w, ln2b, w1s_b, b1, w2s_b, b2, (float*)d_out);
}